// Round 11
// baseline (990.974 us; speedup 1.0000x reference)
//
#include <hip/hip_runtime.h>
#include <hip/hip_bf16.h>
#include <math.h>

// ---------------- problem constants ----------------
#define T_TOK 8192
#define HID   2048
#define NH    16
#define HD    128
#define SEQ   1024
#define NB    8
#define QKVN  6144   // q|k|v concatenated

typedef __bf16 bf16x8 __attribute__((ext_vector_type(8)));
typedef float  f32x4  __attribute__((ext_vector_type(4)));

// ---------------- cast x fp32 -> bf16 ----------------
__global__ void cast_x_kernel(const float* __restrict__ in,
                              __hip_bfloat16* __restrict__ out, int n) {
  int i = blockIdx.x * blockDim.x + threadIdx.x;
  int base = i * 8;
  if (base >= n) return;
  const float4* p = (const float4*)(in + base);
  float4 a = p[0], b = p[1];
  union { uint4 u; __hip_bfloat16 h[8]; } o;
  o.h[0] = __float2bfloat16(a.x); o.h[1] = __float2bfloat16(a.y);
  o.h[2] = __float2bfloat16(a.z); o.h[3] = __float2bfloat16(a.w);
  o.h[4] = __float2bfloat16(b.x); o.h[5] = __float2bfloat16(b.y);
  o.h[6] = __float2bfloat16(b.z); o.h[7] = __float2bfloat16(b.w);
  *(uint4*)(out + base) = o.u;
}

// ---------------- transpose-cast w fp32 [K][N] -> bf16 [N][K] ----------------
__global__ void transpose_cast_kernel(const float* __restrict__ src,
                                      __hip_bfloat16* __restrict__ dst) {
  __shared__ float tile[32][33];
  int n0 = blockIdx.x * 32, k0 = blockIdx.y * 32;
  int tx = threadIdx.x, ty = threadIdx.y;  // 32 x 8
  for (int j = 0; j < 32; j += 8)
    tile[ty + j][tx] = src[(size_t)(k0 + ty + j) * HID + n0 + tx];
  __syncthreads();
  for (int j = 0; j < 32; j += 8)
    dst[(size_t)(n0 + ty + j) * HID + k0 + tx] = __float2bfloat16(tile[tx][ty + j]);
}

// ---------------- bf16 GEMM: C[M,N] = A[M,K] * Bt[N,K]^T ----------------
// 128x128 tile, BK=32, 4 waves (2x2), 4x4 16x16x32 frags per wave.
// Reg-staged LDS fill. OUT_BF16 selects bf16 vs fp32 C-store.
template <bool OUT_BF16>
__global__ __launch_bounds__(256)
void gemm_bf16(const __hip_bfloat16* __restrict__ A,
               const __hip_bfloat16* __restrict__ Bt,
               void* __restrict__ C, int M, int N, int K) {
  __shared__ __hip_bfloat16 As[128 * 32];  // row-major [128][32]
  __shared__ __hip_bfloat16 Bs[128 * 32];
  const int tid = threadIdx.x;
  const int lane = tid & 63;
  const int wid = tid >> 6;
  const int wr = wid >> 1, wc = wid & 1;
  const int m0 = blockIdx.y * 128;
  const int n0 = blockIdx.x * 128;

  f32x4 acc[4][4] = {};

  for (int kt = 0; kt < K; kt += 32) {
#pragma unroll
    for (int p = 0; p < 2; ++p) {
      int c = p * 256 + tid;
      int row = c >> 2, col = (c & 3) * 8;
      *(uint4*)&As[row * 32 + col] =
          *(const uint4*)(A + (size_t)(m0 + row) * K + kt + col);
      *(uint4*)&Bs[row * 32 + col] =
          *(const uint4*)(Bt + (size_t)(n0 + row) * K + kt + col);
    }
    __syncthreads();

    bf16x8 af[4], bf[4];
#pragma unroll
    for (int m = 0; m < 4; ++m) {
      int row = wr * 64 + m * 16 + (lane & 15);
      af[m] = *(const bf16x8*)((const char*)As + row * 64 + (lane >> 4) * 16);
    }
#pragma unroll
    for (int n = 0; n < 4; ++n) {
      int row = wc * 64 + n * 16 + (lane & 15);
      bf[n] = *(const bf16x8*)((const char*)Bs + row * 64 + (lane >> 4) * 16);
    }
#pragma unroll
    for (int m = 0; m < 4; ++m)
#pragma unroll
      for (int n = 0; n < 4; ++n)
        acc[m][n] = __builtin_amdgcn_mfma_f32_16x16x32_bf16(af[m], bf[n], acc[m][n], 0, 0, 0);
    __syncthreads();
  }

  // epilogue: row=(lane>>4)*4+reg, col=lane&15 within each 16x16 frag
#pragma unroll
  for (int m = 0; m < 4; ++m) {
    int row = m0 + wr * 64 + m * 16 + ((lane >> 4) << 2);
#pragma unroll
    for (int r = 0; r < 4; ++r) {
#pragma unroll
      for (int n = 0; n < 4; ++n) {
        int col = n0 + wc * 64 + n * 16 + (lane & 15);
        float v = acc[m][n][r];
        if (OUT_BF16)
          ((__hip_bfloat16*)C)[(size_t)(row + r) * N + col] = __float2bfloat16(v);
        else
          ((float*)C)[(size_t)(row + r) * N + col] = v;
      }
    }
  }
}

// ---------------- RoPE in-place on q,k of qkv [T][6144] ----------------
__global__ void rope_kernel(__hip_bfloat16* __restrict__ qkv,
                            const int* __restrict__ context_lens) {
  int idx = blockIdx.x * blockDim.x + threadIdx.x;  // T*NH*64
  if (idx >= T_TOK * NH * 64) return;
  int d2 = idx & 63;
  int h = (idx >> 6) & 15;
  int t = idx >> 10;
  int b = t >> 10;
  float pos = (float)(context_lens[b] + (t & 1023));
  float freq = expf((float)d2 * (-9.210340371976184f / 64.0f));  // 10000^(-d2/64)
  float ang = pos * freq;
  float s, c;
  sincosf(ang, &s, &c);
  size_t base = (size_t)t * QKVN + h * HD + d2;
  float x1 = __bfloat162float(qkv[base]);
  float x2 = __bfloat162float(qkv[base + 64]);
  qkv[base]      = __float2bfloat16(x1 * c - x2 * s);
  qkv[base + 64] = __float2bfloat16(x1 * s + x2 * c);
  float y1 = __bfloat162float(qkv[base + HID]);
  float y2 = __bfloat162float(qkv[base + HID + 64]);
  qkv[base + HID]      = __float2bfloat16(y1 * c - y2 * s);
  qkv[base + HID + 64] = __float2bfloat16(y1 * s + y2 * c);
}

// ---------------- flash attention, causal, per (b,h,64-row q-tile) ----------------
// 4 waves x 16 q-rows, KVBLK=32, D=128.
__global__ __launch_bounds__(256)
void attn_kernel(const __hip_bfloat16* __restrict__ qkv,
                 __hip_bfloat16* __restrict__ attn) {
  const int qt = blockIdx.x;   // 0..15
  const int h = blockIdx.y;    // 0..15
  const int b = blockIdx.z;    // 0..7
  const int tid = threadIdx.x, lane = tid & 63, wid = tid >> 6;
  const int q0 = qt * 64;
  const size_t seq_base = (size_t)b * SEQ;

  __shared__ __hip_bfloat16 Ks[32][136];   // padded: 272B rows -> 2-way (free)
  __shared__ __hip_bfloat16 Vt[128][40];   // transposed V, 80B rows
  __shared__ __hip_bfloat16 Pl[4][16][40]; // per-wave P

  bf16x8 qf[4];
  {
    int t = q0 + wid * 16 + (lane & 15);
    const __hip_bfloat16* qp = qkv + (seq_base + t) * QKVN + h * HD + (lane >> 4) * 8;
#pragma unroll
    for (int kc = 0; kc < 4; ++kc) qf[kc] = *(const bf16x8*)(qp + kc * 32);
  }

  f32x4 acc_o[8] = {};
  float mrow[4] = {-INFINITY, -INFINITY, -INFINITY, -INFINITY};
  float lrow[4] = {0.f, 0.f, 0.f, 0.f};
  const float scale = 0.08838834764831845f;  // 1/sqrt(128)

  const int ntiles = (q0 + 64) / 32;
  for (int kt = 0; kt < ntiles; ++kt) {
    const int kv0 = kt * 32;
    __syncthreads();
#pragma unroll
    for (int j = 0; j < 2; ++j) {
      int c = j * 256 + tid;
      int row = c >> 4, col = (c & 15) * 8;
      const __hip_bfloat16* kp = qkv + (seq_base + kv0 + row) * QKVN + HID + h * HD + col;
      *(uint4*)&Ks[row][col] = *(const uint4*)kp;
      const __hip_bfloat16* vp = qkv + (seq_base + kv0 + row) * QKVN + 2 * HID + h * HD + col;
      uint4 vd = *(const uint4*)vp;
      const ushort* vs = (const ushort*)&vd;
#pragma unroll
      for (int i = 0; i < 8; ++i) *(ushort*)&Vt[col + i][row] = vs[i];
    }
    __syncthreads();

    f32x4 s[2];
#pragma unroll
    for (int ct = 0; ct < 2; ++ct) {
      f32x4 a = {};
      int row = ct * 16 + (lane & 15);
#pragma unroll
      for (int kc = 0; kc < 4; ++kc) {
        bf16x8 kf = *(const bf16x8*)((const char*)&Ks[0][0] + row * 272 + kc * 64 + (lane >> 4) * 16);
        a = __builtin_amdgcn_mfma_f32_16x16x32_bf16(qf[kc], kf, a, 0, 0, 0);
      }
      s[ct] = a;
    }

    int qrow_base = q0 + wid * 16 + (lane >> 4) * 4;
#pragma unroll
    for (int ct = 0; ct < 2; ++ct) {
      int kvcol = kv0 + ct * 16 + (lane & 15);
#pragma unroll
      for (int r = 0; r < 4; ++r) {
        float v = s[ct][r] * scale;
        s[ct][r] = (kvcol > qrow_base + r) ? -INFINITY : v;
      }
    }

    float corr[4];
#pragma unroll
    for (int r = 0; r < 4; ++r) {
      float t = fmaxf(s[0][r], s[1][r]);
      t = fmaxf(t, __shfl_xor(t, 1));
      t = fmaxf(t, __shfl_xor(t, 2));
      t = fmaxf(t, __shfl_xor(t, 4));
      t = fmaxf(t, __shfl_xor(t, 8));
      float mnew = fmaxf(mrow[r], t);
      corr[r] = __expf(mrow[r] - mnew);
      float p0 = __expf(s[0][r] - mnew);
      float p1 = __expf(s[1][r] - mnew);
      float sum = p0 + p1;
      sum += __shfl_xor(sum, 1);
      sum += __shfl_xor(sum, 2);
      sum += __shfl_xor(sum, 4);
      sum += __shfl_xor(sum, 8);
      lrow[r] = lrow[r] * corr[r] + sum;
      mrow[r] = mnew;
      int prow = (lane >> 4) * 4 + r;
      Pl[wid][prow][0 * 16 + (lane & 15)] = __float2bfloat16(p0);
      Pl[wid][prow][1 * 16 + (lane & 15)] = __float2bfloat16(p1);
    }

#pragma unroll
    for (int n = 0; n < 8; ++n)
#pragma unroll
      for (int r = 0; r < 4; ++r) acc_o[n][r] *= corr[r];

    bf16x8 pa = *(const bf16x8*)((const char*)&Pl[wid][0][0] + (lane & 15) * 80 + (lane >> 4) * 16);
#pragma unroll
    for (int n = 0; n < 8; ++n) {
      bf16x8 vf = *(const bf16x8*)((const char*)&Vt[0][0] + (n * 16 + (lane & 15)) * 80 + (lane >> 4) * 16);
      acc_o[n] = __builtin_amdgcn_mfma_f32_16x16x32_bf16(pa, vf, acc_o[n], 0, 0, 0);
    }
  }

#pragma unroll
  for (int n = 0; n < 8; ++n)
#pragma unroll
    for (int r = 0; r < 4; ++r) {
      int qrow = q0 + wid * 16 + (lane >> 4) * 4 + r;
      float v = acc_o[n][r] / lrow[r];
      attn[(seq_base + qrow) * HID + h * HD + n * 16 + (lane & 15)] = __float2bfloat16(v);
    }
}

// ---------------- launch ----------------
extern "C" void kernel_launch(void* const* d_in, const int* in_sizes, int n_in,
                              void* d_out, int out_size, void* d_ws, size_t ws_size,
                              hipStream_t stream) {
  const float* x  = (const float*)d_in[0];
  const int* ctx  = (const int*)d_in[2];
  const float* wq = (const float*)d_in[3];
  const float* wk = (const float*)d_in[4];
  const float* wv = (const float*)d_in[5];
  const float* wo = (const float*)d_in[6];

  // workspace layout (168 MB):
  //   [0,       33.5MB)  xbf — bf16 x; REUSED as attn output after QKV GEMM
  //   [33.5MB,  58.7MB)  wqkvT — bf16 [6144][2048]
  //   [58.7MB,  67.1MB)  woT   — bf16 [2048][2048]
  //   [67.1MB, 167.8MB)  qkv   — bf16 [8192][6144]
  char* ws = (char*)d_ws;
  __hip_bfloat16* xbf   = (__hip_bfloat16*)(ws);
  __hip_bfloat16* wqkvT = (__hip_bfloat16*)(ws + 33554432);
  __hip_bfloat16* woT   = (__hip_bfloat16*)(ws + 58720256);
  __hip_bfloat16* qkv   = (__hip_bfloat16*)(ws + 67108864);
  __hip_bfloat16* attn  = (__hip_bfloat16*)(ws);  // aliases xbf (dead by then)

  cast_x_kernel<<<T_TOK * HID / 8 / 256, 256, 0, stream>>>(x, xbf, T_TOK * HID);

  dim3 tb(32, 8), tg(HID / 32, HID / 32);
  transpose_cast_kernel<<<tg, tb, 0, stream>>>(wq, wqkvT);
  transpose_cast_kernel<<<tg, tb, 0, stream>>>(wk, wqkvT + (size_t)HID * HID);
  transpose_cast_kernel<<<tg, tb, 0, stream>>>(wv, wqkvT + (size_t)2 * HID * HID);
  transpose_cast_kernel<<<tg, tb, 0, stream>>>(wo, woT);

  gemm_bf16<true><<<dim3(QKVN / 128, T_TOK / 128), 256, 0, stream>>>(
      xbf, wqkvT, qkv, T_TOK, QKVN, HID);

  rope_kernel<<<T_TOK * NH * 64 / 256, 256, 0, stream>>>(qkv, ctx);

  attn_kernel<<<dim3(SEQ / 64, NH, NB), 256, 0, stream>>>(qkv, attn);

  // FP32 output: the reference returns float32, so d_out is float*.
  gemm_bf16<false><<<dim3(HID / 128, T_TOK / 128), 256, 0, stream>>>(
      attn, woT, (void*)d_out, T_TOK, HID, HID);
}

// Round 13
// 797.737 us; speedup vs baseline: 1.2422x; 1.2422x over previous
//
#include <hip/hip_runtime.h>
#include <hip/hip_bf16.h>
#include <math.h>

// ---------------- problem constants ----------------
#define T_TOK 8192
#define HID   2048
#define NH    16
#define HD    128
#define SEQ   1024
#define NB    8
#define QKVN  6144   // q|k|v concatenated

typedef __bf16 bf16x8 __attribute__((ext_vector_type(8)));
typedef float  f32x4  __attribute__((ext_vector_type(4)));

__device__ __forceinline__ void gload_lds16(const void* g, void* l) {
  __builtin_amdgcn_global_load_lds(
      (const __attribute__((address_space(1))) void*)g,
      (__attribute__((address_space(3))) void*)l, 16, 0, 0);
}

// ---------------- cast x fp32 -> bf16 ----------------
__global__ void cast_x_kernel(const float* __restrict__ in,
                              __hip_bfloat16* __restrict__ out, int n) {
  int i = blockIdx.x * blockDim.x + threadIdx.x;
  int base = i * 8;
  if (base >= n) return;
  const float4* p = (const float4*)(in + base);
  float4 a = p[0], b = p[1];
  union { uint4 u; __hip_bfloat16 h[8]; } o;
  o.h[0] = __float2bfloat16(a.x); o.h[1] = __float2bfloat16(a.y);
  o.h[2] = __float2bfloat16(a.z); o.h[3] = __float2bfloat16(a.w);
  o.h[4] = __float2bfloat16(b.x); o.h[5] = __float2bfloat16(b.y);
  o.h[6] = __float2bfloat16(b.z); o.h[7] = __float2bfloat16(b.w);
  *(uint4*)(out + base) = o.u;
}

// ---------------- transpose-cast w fp32 [K][N] -> bf16 [N][K] ----------------
__global__ void transpose_cast_kernel(const float* __restrict__ src,
                                      __hip_bfloat16* __restrict__ dst) {
  __shared__ float tile[32][33];
  int n0 = blockIdx.x * 32, k0 = blockIdx.y * 32;
  int tx = threadIdx.x, ty = threadIdx.y;  // 32 x 8
  for (int j = 0; j < 32; j += 8)
    tile[ty + j][tx] = src[(size_t)(k0 + ty + j) * HID + n0 + tx];
  __syncthreads();
  for (int j = 0; j < 32; j += 8)
    dst[(size_t)(n0 + ty + j) * HID + k0 + tx] = __float2bfloat16(tile[tx][ty + j]);
}

// ---------------- V transpose: qkv v-slice [t][d] -> vt[b][h][d][s] ----------
__global__ void vtrans_kernel(const __hip_bfloat16* __restrict__ qkv,
                              __hip_bfloat16* __restrict__ vt) {
  __shared__ __hip_bfloat16 tile[32][33];
  const int s0 = blockIdx.x * 32;       // seq tile
  const int d0 = blockIdx.y * 32;       // head-dim tile
  const int bh = blockIdx.z;            // b*NH + h
  const int b = bh >> 4, h = bh & 15;
  const int tx = threadIdx.x, ty = threadIdx.y;  // 32 x 8
  for (int j = 0; j < 32; j += 8)
    tile[ty + j][tx] = qkv[(size_t)(b * SEQ + s0 + ty + j) * QKVN + 2 * HID + h * HD + d0 + tx];
  __syncthreads();
  for (int j = 0; j < 32; j += 8)
    vt[(size_t)(bh * HD + d0 + ty + j) * SEQ + s0 + tx] = tile[tx][ty + j];
}

// ---------------- bf16 GEMM: C[M,N] = A[M,K](lda) * Bt[N,K]^T ----------------
// 128x128 tile, BK=32, 4 waves (2x2), global_load_lds width-16 staging.
template <bool OUT_BF16>
__global__ __launch_bounds__(256)
void gemm_bf16(const __hip_bfloat16* __restrict__ A,
               const __hip_bfloat16* __restrict__ Bt,
               void* __restrict__ C, int M, int N, int K, int lda) {
  __shared__ __hip_bfloat16 As[128 * 32];  // linear row-major [128][32]
  __shared__ __hip_bfloat16 Bs[128 * 32];
  const int tid = threadIdx.x;
  const int lane = tid & 63;
  const int wid = tid >> 6;
  const int wr = wid >> 1, wc = wid & 1;
  const int m0 = blockIdx.y * 128;
  const int n0 = blockIdx.x * 128;

  f32x4 acc[4][4] = {};

  for (int kt = 0; kt < K; kt += 32) {
    // stage A,B tiles: 512 chunks of 16B; chunk c -> row=c>>2, col8=(c&3)*8
#pragma unroll
    for (int j = 0; j < 2; ++j) {
      int cw = j * 256 + wid * 64;          // wave-uniform chunk base
      int c = cw + lane;
      gload_lds16(A + (size_t)(m0 + (c >> 2)) * lda + kt + (c & 3) * 8,
                  (char*)As + cw * 16);
      gload_lds16(Bt + (size_t)(n0 + (c >> 2)) * K + kt + (c & 3) * 8,
                  (char*)Bs + cw * 16);
    }
    __syncthreads();

    bf16x8 af[4], bf[4];
#pragma unroll
    for (int m = 0; m < 4; ++m) {
      int row = wr * 64 + m * 16 + (lane & 15);
      af[m] = *(const bf16x8*)((const char*)As + row * 64 + (lane >> 4) * 16);
    }
#pragma unroll
    for (int n = 0; n < 4; ++n) {
      int row = wc * 64 + n * 16 + (lane & 15);
      bf[n] = *(const bf16x8*)((const char*)Bs + row * 64 + (lane >> 4) * 16);
    }
#pragma unroll
    for (int m = 0; m < 4; ++m)
#pragma unroll
      for (int n = 0; n < 4; ++n)
        acc[m][n] = __builtin_amdgcn_mfma_f32_16x16x32_bf16(af[m], bf[n], acc[m][n], 0, 0, 0);
    __syncthreads();
  }

  // epilogue: row=(lane>>4)*4+reg, col=lane&15 within each 16x16 frag
#pragma unroll
  for (int m = 0; m < 4; ++m) {
    int row = m0 + wr * 64 + m * 16 + ((lane >> 4) << 2);
#pragma unroll
    for (int r = 0; r < 4; ++r) {
#pragma unroll
      for (int n = 0; n < 4; ++n) {
        int col = n0 + wc * 64 + n * 16 + (lane & 15);
        float v = acc[m][n][r];
        if (OUT_BF16)
          ((__hip_bfloat16*)C)[(size_t)(row + r) * N + col] = __float2bfloat16(v);
        else
          ((float*)C)[(size_t)(row + r) * N + col] = v;
      }
    }
  }
}

// ---------------- RoPE in-place on q,k of qkv [T][6144] ----------------
__global__ void rope_kernel(__hip_bfloat16* __restrict__ qkv,
                            const int* __restrict__ context_lens) {
  int idx = blockIdx.x * blockDim.x + threadIdx.x;  // T*NH*64
  if (idx >= T_TOK * NH * 64) return;
  int d2 = idx & 63;
  int h = (idx >> 6) & 15;
  int t = idx >> 10;
  int b = t >> 10;
  float pos = (float)(context_lens[b] + (t & 1023));
  float freq = expf((float)d2 * (-9.210340371976184f / 64.0f));  // 10000^(-d2/64)
  float ang = pos * freq;
  float s, c;
  sincosf(ang, &s, &c);
  size_t base = (size_t)t * QKVN + h * HD + d2;
  float x1 = __bfloat162float(qkv[base]);
  float x2 = __bfloat162float(qkv[base + 64]);
  qkv[base]      = __float2bfloat16(x1 * c - x2 * s);
  qkv[base + 64] = __float2bfloat16(x1 * s + x2 * c);
  float y1 = __bfloat162float(qkv[base + HID]);
  float y2 = __bfloat162float(qkv[base + HID + 64]);
  qkv[base + HID]      = __float2bfloat16(y1 * c - y2 * s);
  qkv[base + HID + 64] = __float2bfloat16(y1 * s + y2 * c);
}

// ---------------- flash attention, causal, per (b,h,64-row q-tile) ----------------
// 4 waves x 16 q-rows, KVBLK=32, D=128. V from pre-transposed global vt.
// Output written IN-PLACE into the q-slice of qkv (each block owns its q rows).
__global__ __launch_bounds__(256)
void attn_kernel(__hip_bfloat16* __restrict__ qkv,
                 const __hip_bfloat16* __restrict__ vt) {
  const int qt = blockIdx.x;   // 0..15
  const int h = blockIdx.y;    // 0..15
  const int b = blockIdx.z;    // 0..7
  const int bh = b * NH + h;
  const int tid = threadIdx.x, lane = tid & 63, wid = tid >> 6;
  const int q0 = qt * 64;
  const size_t seq_base = (size_t)b * SEQ;

  __shared__ __hip_bfloat16 Ks[32][136];   // 272B rows -> ~2-way (free)
  __shared__ __hip_bfloat16 Vts[128][40];  // V^T tile, 80B rows -> 2-way reads
  __shared__ __hip_bfloat16 Pl[4][16][40]; // per-wave P

  bf16x8 qf[4];
  {
    int t = q0 + wid * 16 + (lane & 15);
    const __hip_bfloat16* qp = qkv + (seq_base + t) * QKVN + h * HD + (lane >> 4) * 8;
#pragma unroll
    for (int kc = 0; kc < 4; ++kc) qf[kc] = *(const bf16x8*)(qp + kc * 32);
  }

  f32x4 acc_o[8] = {};
  float mrow[4] = {-INFINITY, -INFINITY, -INFINITY, -INFINITY};
  float lrow[4] = {0.f, 0.f, 0.f, 0.f};
  const float scale = 0.08838834764831845f;  // 1/sqrt(128)

  const int ntiles = (q0 + 64) / 32;
  for (int kt = 0; kt < ntiles; ++kt) {
    const int kv0 = kt * 32;
    __syncthreads();
    // stage K rows (vector) + V^T rows from global vt (vector) — no scalar LDS ops
#pragma unroll
    for (int j = 0; j < 2; ++j) {
      int c = j * 256 + tid;
      int krow = c >> 4, kcol = (c & 15) * 8;
      *(uint4*)&Ks[krow][kcol] = *(const uint4*)(
          qkv + (seq_base + kv0 + krow) * QKVN + HID + h * HD + kcol);
      int vrow = c >> 2, vseg = (c & 3) * 8;
      *(uint4*)&Vts[vrow][vseg] = *(const uint4*)(
          vt + (size_t)(bh * HD + vrow) * SEQ + kv0 + vseg);
    }
    __syncthreads();

    // QK^T: 16x32 scores per wave
    f32x4 s[2];
#pragma unroll
    for (int ct = 0; ct < 2; ++ct) {
      f32x4 a = {};
      int row = ct * 16 + (lane & 15);
#pragma unroll
      for (int kc = 0; kc < 4; ++kc) {
        bf16x8 kf = *(const bf16x8*)((const char*)&Ks[0][0] + row * 272 + kc * 64 + (lane >> 4) * 16);
        a = __builtin_amdgcn_mfma_f32_16x16x32_bf16(qf[kc], kf, a, 0, 0, 0);
      }
      s[ct] = a;
    }

    // mask + scale
    int qrow_base = q0 + wid * 16 + (lane >> 4) * 4;
#pragma unroll
    for (int ct = 0; ct < 2; ++ct) {
      int kvcol = kv0 + ct * 16 + (lane & 15);
#pragma unroll
      for (int r = 0; r < 4; ++r) {
        float v = s[ct][r] * scale;
        s[ct][r] = (kvcol > qrow_base + r) ? -INFINITY : v;
      }
    }

    // online softmax (per q-row, across 16 lanes of the group)
    float corr[4];
#pragma unroll
    for (int r = 0; r < 4; ++r) {
      float t = fmaxf(s[0][r], s[1][r]);
      t = fmaxf(t, __shfl_xor(t, 1));
      t = fmaxf(t, __shfl_xor(t, 2));
      t = fmaxf(t, __shfl_xor(t, 4));
      t = fmaxf(t, __shfl_xor(t, 8));
      float mnew = fmaxf(mrow[r], t);
      corr[r] = __expf(mrow[r] - mnew);
      float p0 = __expf(s[0][r] - mnew);
      float p1 = __expf(s[1][r] - mnew);
      float sum = p0 + p1;
      sum += __shfl_xor(sum, 1);
      sum += __shfl_xor(sum, 2);
      sum += __shfl_xor(sum, 4);
      sum += __shfl_xor(sum, 8);
      lrow[r] = lrow[r] * corr[r] + sum;
      mrow[r] = mnew;
      int prow = (lane >> 4) * 4 + r;
      Pl[wid][prow][0 * 16 + (lane & 15)] = __float2bfloat16(p0);
      Pl[wid][prow][1 * 16 + (lane & 15)] = __float2bfloat16(p1);
    }

    // rescale O
#pragma unroll
    for (int n = 0; n < 8; ++n)
#pragma unroll
      for (int r = 0; r < 4; ++r) acc_o[n][r] *= corr[r];

    // PV (intra-wave Pl dependency, no barrier needed)
    bf16x8 pa = *(const bf16x8*)((const char*)&Pl[wid][0][0] + (lane & 15) * 80 + (lane >> 4) * 16);
#pragma unroll
    for (int n = 0; n < 8; ++n) {
      bf16x8 vf = *(const bf16x8*)((const char*)&Vts[0][0] + (n * 16 + (lane & 15)) * 80 + (lane >> 4) * 16);
      acc_o[n] = __builtin_amdgcn_mfma_f32_16x16x32_bf16(pa, vf, acc_o[n], 0, 0, 0);
    }
  }

  // epilogue: normalize + store bf16 into the q-slice of qkv (in-place)
#pragma unroll
  for (int n = 0; n < 8; ++n)
#pragma unroll
    for (int r = 0; r < 4; ++r) {
      int qrow = q0 + wid * 16 + (lane >> 4) * 4 + r;
      float v = acc_o[n][r] / lrow[r];
      qkv[(seq_base + qrow) * QKVN + h * HD + n * 16 + (lane & 15)] = __float2bfloat16(v);
    }
}

// ---------------- launch ----------------
extern "C" void kernel_launch(void* const* d_in, const int* in_sizes, int n_in,
                              void* d_out, int out_size, void* d_ws, size_t ws_size,
                              hipStream_t stream) {
  const float* x  = (const float*)d_in[0];
  const int* ctx  = (const int*)d_in[2];
  const float* wq = (const float*)d_in[3];
  const float* wk = (const float*)d_in[4];
  const float* wv = (const float*)d_in[5];
  const float* wo = (const float*)d_in[6];

  // workspace (168 MB):
  //   [0,       33.5MB)  xbf — bf16 x; REUSED as vt[b][h][128][1024] after QKV GEMM
  //   [33.5MB,  58.7MB)  wqkvT — bf16 [6144][2048]
  //   [58.7MB,  67.1MB)  woT   — bf16 [2048][2048]
  //   [67.1MB, 167.8MB)  qkv   — bf16 [8192][6144]; attn O overwrites its q-slice
  char* ws = (char*)d_ws;
  __hip_bfloat16* xbf   = (__hip_bfloat16*)(ws);
  __hip_bfloat16* vt    = (__hip_bfloat16*)(ws);            // aliases xbf (dead)
  __hip_bfloat16* wqkvT = (__hip_bfloat16*)(ws + 33554432);
  __hip_bfloat16* woT   = (__hip_bfloat16*)(ws + 58720256);
  __hip_bfloat16* qkv   = (__hip_bfloat16*)(ws + 67108864);

  cast_x_kernel<<<T_TOK * HID / 8 / 256, 256, 0, stream>>>(x, xbf, T_TOK * HID);

  dim3 tb(32, 8), tg(HID / 32, HID / 32);
  transpose_cast_kernel<<<tg, tb, 0, stream>>>(wq, wqkvT);
  transpose_cast_kernel<<<tg, tb, 0, stream>>>(wk, wqkvT + (size_t)HID * HID);
  transpose_cast_kernel<<<tg, tb, 0, stream>>>(wv, wqkvT + (size_t)2 * HID * HID);
  transpose_cast_kernel<<<tg, tb, 0, stream>>>(wo, woT);

  gemm_bf16<true><<<dim3(QKVN / 128, T_TOK / 128), 256, 0, stream>>>(
      xbf, wqkvT, qkv, T_TOK, QKVN, HID, HID);

  rope_kernel<<<T_TOK * NH * 64 / 256, 256, 0, stream>>>(qkv, ctx);

  // xbf is dead now; build vt in its place
  vtrans_kernel<<<dim3(SEQ / 32, HD / 32, NB * NH), dim3(32, 8), 0, stream>>>(qkv, vt);

  attn_kernel<<<dim3(SEQ / 64, NH, NB), 256, 0, stream>>>(qkv, vt);

  // FP32 output; A = attn output living in qkv's q-slice (lda = 6144)
  gemm_bf16<false><<<dim3(HID / 128, T_TOK / 128), 256, 0, stream>>>(
      qkv, woT, (void*)d_out, T_TOK, HID, HID, QKVN);
}